// Round 14
// baseline (53.372 us; speedup 1.0000x reference)
//
#include <hip/hip_runtime.h>

typedef __attribute__((ext_vector_type(8))) short short8;
typedef __attribute__((ext_vector_type(4))) float floatx4;
typedef unsigned int uint;
typedef unsigned short ushort;

#define BATCH 16
#define CH 64
#define NPIX 16384   // 128*128
#define TWOC 128

__device__ __forceinline__ ushort f2bf(float f) {   // RNE f32 -> bf16 bits
    uint u = __float_as_uint(f);
    u += 0x7FFFu + ((u >> 16) & 1u);
    return (ushort)(u >> 16);
}
__device__ __forceinline__ uint pk2(float lo, float hi) {
    return (uint)f2bf(lo) | ((uint)f2bf(hi) << 16);
}

// async global->LDS DMA, 16B per lane (dest = wave-uniform base + lane*16)
typedef const __attribute__((address_space(1))) void gas_void;
typedef __attribute__((address_space(3))) void las_void;
__device__ __forceinline__ void gload16(const void* g, void* l) {
    __builtin_amdgcn_global_load_lds((gas_void*)g, (las_void*)l, 16, 0, 0);
}

// ---------------------------------------------------------------------------
// Kernel 1: partial Gram matrices G[b][map][64][64] = sum_n V[c,n]*V[d,n]
// map 0 = template (t_attn, needed iff omega!=0); map 1 = roi (r_attn, iff
// gamma!=0). Early-exits when the multiplier is exactly 0 (contribution is
// exactly zero -- algebraic short-circuit, deterministic).
// ---------------------------------------------------------------------------
__global__ __launch_bounds__(256) void gram_kernel(
    const float* __restrict__ tmap, const float* __restrict__ rmap,
    const float* __restrict__ gamma, const float* __restrict__ omega,
    float* __restrict__ G)
{
    const int map = blockIdx.y;
    const float mult = (map == 0) ? omega[0] : gamma[0];
    if (mult == 0.f) return;

    __shared__ float tile[64][68];
    const int chunk = blockIdx.x;
    const int b     = blockIdx.z;
    const float* x = (map == 0 ? tmap : rmap) + (size_t)b * CH * NPIX + chunk * 512;
    const int t  = threadIdx.x;
    const int ti = t >> 4;
    const int tj = t & 15;

    float acc[4][4];
#pragma unroll
    for (int i = 0; i < 4; ++i)
#pragma unroll
        for (int j = 0; j < 4; ++j) acc[i][j] = 0.f;

    for (int tt = 0; tt < 8; ++tt) {
        const int col0 = tt * 64;
#pragma unroll
        for (int k = 0; k < 16; ++k) {
            int e = t + 256 * k;
            int c = e >> 6, col = e & 63;
            tile[c][col] = x[(size_t)c * NPIX + col0 + col];
        }
        __syncthreads();
#pragma unroll 8
        for (int n = 0; n < 64; n += 2) {
            float2 av[4], bv[4];
#pragma unroll
            for (int i = 0; i < 4; ++i) av[i] = *(const float2*)&tile[ti + 16 * i][n];
#pragma unroll
            for (int j = 0; j < 4; ++j) bv[j] = *(const float2*)&tile[tj + 16 * j][n];
#pragma unroll
            for (int i = 0; i < 4; ++i)
#pragma unroll
                for (int j = 0; j < 4; ++j) {
                    acc[i][j] += av[i].x * bv[j].x;
                    acc[i][j] += av[i].y * bv[j].y;
                }
        }
        __syncthreads();
    }
    float* Gp = G + ((size_t)(b * 2 + map) << 12);
#pragma unroll
    for (int i = 0; i < 4; ++i)
#pragma unroll
        for (int j = 0; j < 4; ++j)
            atomicAdd(&Gp[(ti + 16 * i) * 64 + (tj + 16 * j)], acc[i][j]);
}

// ---------------------------------------------------------------------------
// Kernel 2 (FUSED finalize + MFMA GEMM, 512-px tiles = 2KB sequential runs):
//   out[b](64 x 16384) = M[b](64x128) @ X(128x16384) + bias
//   M[o][k] = conv_w[o][k] + (k<64 ? gamma*(W1@r_attn)[o][k]
//                                  : omega*(W2@t_attn)[o][k-64])
// Tile 64 och x 512 px, K in 4 chunks of 32 rows. Per wave per chunk:
// 8 rows x 2 BACK-TO-BACK 1KB DMA ops (2KB contiguous per row) -- twice the
// DRAM-page run length of r12, half the blocks sharing each row.
// Xs[2][32][512] f32 ping-pong (128KB) + Ms 16KB = 144KB -> 1 block/CU,
// grid 32x16 = 512 blocks. Counted s_waitcnt vmcnt(16), raw s_barrier,
// plain dword stores (NT reverted: r13 showed +8MB WRITE, no FETCH gain).
// ---------------------------------------------------------------------------
__global__ __launch_bounds__(256, 1) void out_kernel(
    const float* __restrict__ tmap, const float* __restrict__ rmap,
    const float* __restrict__ G, const float* __restrict__ gamma,
    const float* __restrict__ omega, const float* __restrict__ conv_w,
    const float* __restrict__ conv_b, float* __restrict__ out)
{
    __shared__ __align__(16) uint   Xs[2][32][512];   // 128 KB ping-pong
    __shared__ __align__(16) ushort Ms[8192];         // 16 KB A-fragments

    const int b   = blockIdx.y;
    const int t   = threadIdx.x;
    const int w   = t >> 6;
    const int l   = t & 63;
    const int lg  = l >> 4;
    const int lj  = l & 15;
    const int px0 = blockIdx.x * 512;

    const float gam = gamma[0], om = omega[0];

    // ---- build M fragments in LDS ----
    if (gam != 0.f || om != 0.f) {
        float* attnf = (float*)&Xs[0][0][0];          // 32 KB staging, pre-DMA
        if (t < 128) {
            const int map = t >> 6, i = t & 63;
            const float need = (map == 0) ? om : gam;
            if (need != 0.f) {
                const float* Grow = G + ((size_t)(b * 2 + map) << 12) + i * 64;
                float mn = Grow[0];
                for (int j = 1; j < 64; ++j) mn = fminf(mn, Grow[j]);
                float s = 0.f;
                for (int j = 0; j < 64; ++j) s += expf(mn - Grow[j]);
                const float inv = 1.f / s;
                for (int j = 0; j < 64; ++j)
                    attnf[(map << 12) + i * 64 + j] = expf(mn - Grow[j]) * inv;
            }
        }
        __syncthreads();
#pragma unroll
        for (int j = 0; j < 32; ++j) {
            const int idx = t + 256 * j;
            const int e = idx & 7, ll = (idx >> 3) & 63;
            const int mi = (idx >> 9) & 3, kstep = idx >> 11;
            const int row = mi * 16 + (ll & 15);
            const int k   = kstep * 32 + (ll >> 4) * 8 + e;
            const float* wrow = conv_w + row * TWOC;
            float v = wrow[k];
            if (k < 64) {
                if (gam != 0.f) {
                    float dot = 0.f;
                    for (int c = 0; c < 64; ++c) dot += wrow[c] * attnf[(1 << 12) + c * 64 + k];
                    v += gam * dot;
                }
            } else {
                if (om != 0.f) {
                    float dot = 0.f;
                    for (int c = 0; c < 64; ++c) dot += wrow[64 + c] * attnf[c * 64 + (k - 64)];
                    v += om * dot;
                }
            }
            Ms[idx] = f2bf(v);
        }
        __syncthreads();   // attn reads done; Xs free for DMA; Ms visible
    } else {
        // zero path: M == conv_w, straight repack (no attn, no G)
#pragma unroll
        for (int j = 0; j < 32; ++j) {
            const int idx = t + 256 * j;
            const int e = idx & 7, ll = (idx >> 3) & 63;
            const int mi = (idx >> 9) & 3, kstep = idx >> 11;
            const int row = mi * 16 + (ll & 15);
            const int k   = kstep * 32 + (ll >> 4) * 8 + e;
            Ms[idx] = f2bf(conv_w[row * TWOC + k]);
        }
    }

    const float* tb = tmap + (size_t)b * CH * NPIX + px0;
    const float* rb = rmap + (size_t)b * CH * NPIX + px0;
#define SRC(c) (((c) < 2 ? tb : rb) + (size_t)(((c) & 1) * 32) * NPIX)

    // stage chunk cc into Xs[cc&1]: wave w -> rows [8w,8w+8), 2KB run per row
#define STAGE(cc) do {                                                        \
        const float* _s = SRC(cc);                                            \
        _Pragma("unroll")                                                     \
        for (int i = 0; i < 8; ++i) {                                         \
            const int row = w * 8 + i;                                        \
            gload16(_s + (size_t)row * NPIX + 4 * l,       &Xs[(cc) & 1][row][0]);   \
            gload16(_s + (size_t)row * NPIX + 256 + 4 * l, &Xs[(cc) & 1][row][256]); \
        }                                                                     \
    } while (0)

    // ---- prologue: queue chunks 0 and 1 (16 DMA ops each) ----
    STAGE(0);
    STAGE(1);

    // Ms visible to all waves
    asm volatile("s_waitcnt lgkmcnt(0)" ::: "memory");
    __builtin_amdgcn_s_barrier();
    __builtin_amdgcn_sched_barrier(0);

    floatx4 acc[4][8];
#pragma unroll
    for (int mi = 0; mi < 4; ++mi)
#pragma unroll
        for (int nj = 0; nj < 8; ++nj) acc[mi][nj] = (floatx4){0.f, 0.f, 0.f, 0.f};

#pragma unroll
    for (int c = 0; c < 4; ++c) {
        if (c < 3) { asm volatile("s_waitcnt vmcnt(16) lgkmcnt(0)" ::: "memory"); }
        else       { asm volatile("s_waitcnt vmcnt(0)  lgkmcnt(0)" ::: "memory"); }
        __builtin_amdgcn_sched_barrier(0);
        __builtin_amdgcn_s_barrier();
        __builtin_amdgcn_sched_barrier(0);

        // A-fragments for this chunk (ds_read_b128 x4, compiler-waited)
        short8 a[4];
#pragma unroll
        for (int mi = 0; mi < 4; ++mi)
            a[mi] = *(const short8*)&Ms[((c * 4 + mi) * 64 + l) * 8];

        // compute chunk c from Xs[c&1]; wave w owns px [128w,128w+128)
#pragma unroll
        for (int nj = 0; nj < 8; ++nj) {
            const int pxl = w * 128 + nj * 16 + lj;
            float v[8];
#pragma unroll
            for (int e = 0; e < 8; ++e)
                v[e] = __uint_as_float(Xs[c & 1][8 * lg + e][pxl]);
            uint4 bu;
            bu.x = pk2(v[0], v[1]);
            bu.y = pk2(v[2], v[3]);
            bu.z = pk2(v[4], v[5]);
            bu.w = pk2(v[6], v[7]);
            const short8 bb = *(const short8*)&bu;
#pragma unroll
            for (int mi = 0; mi < 4; ++mi)
                acc[mi][nj] = __builtin_amdgcn_mfma_f32_16x16x32_bf16(
                    a[mi], bb, acc[mi][nj], 0, 0, 0);
        }

        // release buffer
        asm volatile("s_waitcnt lgkmcnt(0)" ::: "memory");
        __builtin_amdgcn_sched_barrier(0);
        __builtin_amdgcn_s_barrier();
        __builtin_amdgcn_sched_barrier(0);

        // refill with chunk c+2
        if (c < 2) STAGE(c + 2);
    }
#undef STAGE
#undef SRC

    // epilogue: C/D layout col=lane&15, row=(lane>>4)*4+reg (guide m89/m91)
    const int pxw = px0 + w * 128;
#pragma unroll
    for (int mi = 0; mi < 4; ++mi) {
#pragma unroll
        for (int r = 0; r < 4; ++r) {
            const int och = mi * 16 + lg * 4 + r;
            const float bv = conv_b[och];
            float* orow = out + ((size_t)b * CH + och) * NPIX;
#pragma unroll
            for (int nj = 0; nj < 8; ++nj)
                orow[pxw + nj * 16 + lj] = acc[mi][nj][r] + bv;
        }
    }
}

// ---------------------------------------------------------------------------
extern "C" void kernel_launch(void* const* d_in, const int* in_sizes, int n_in,
                              void* d_out, int out_size, void* d_ws, size_t ws_size,
                              hipStream_t stream) {
    const float* tmap   = (const float*)d_in[0];
    const float* rmap   = (const float*)d_in[1];
    const float* gamma  = (const float*)d_in[2];
    const float* omega  = (const float*)d_in[3];
    const float* conv_w = (const float*)d_in[4];
    const float* conv_b = (const float*)d_in[5];
    float* out = (float*)d_out;

    // ws layout: G [16][2][4096] fp32 (512 KiB)
    float* G = (float*)d_ws;

    hipMemsetAsync(d_ws, 0, (size_t)BATCH * 2 * 4096 * sizeof(float), stream);

    gram_kernel<<<dim3(32, 2, BATCH), 256, 0, stream>>>(tmap, rmap, gamma, omega, G);
    out_kernel<<<dim3(32, BATCH), 256, 0, stream>>>(tmap, rmap, G, gamma, omega,
                                                    conv_w, conv_b, out);
}

// Round 15
// 45.173 us; speedup vs baseline: 1.1815x; 1.1815x over previous
//
#include <hip/hip_runtime.h>

typedef __attribute__((ext_vector_type(8))) short short8;
typedef __attribute__((ext_vector_type(4))) float floatx4;
typedef unsigned int uint;
typedef unsigned short ushort;

#define BATCH 16
#define CH 64
#define NPIX 16384   // 128*128
#define TWOC 128

__device__ __forceinline__ ushort f2bf(float f) {   // RNE f32 -> bf16 bits
    uint u = __float_as_uint(f);
    u += 0x7FFFu + ((u >> 16) & 1u);
    return (ushort)(u >> 16);
}
__device__ __forceinline__ uint pk2(float lo, float hi) {
    return (uint)f2bf(lo) | ((uint)f2bf(hi) << 16);
}

// async global->LDS DMA, 16B per lane (dest = wave-uniform base + lane*16)
typedef const __attribute__((address_space(1))) void gas_void;
typedef __attribute__((address_space(3))) void las_void;
__device__ __forceinline__ void gload16(const void* g, void* l) {
    __builtin_amdgcn_global_load_lds((gas_void*)g, (las_void*)l, 16, 0, 0);
}

// ---------------------------------------------------------------------------
// Kernel 1: partial Gram matrices G[b][map][64][64] = sum_n V[c,n]*V[d,n]
// map 0 = template (t_attn, needed iff omega!=0); map 1 = roi (r_attn, iff
// gamma!=0). Early-exits when the multiplier is exactly 0 (contribution is
// exactly zero -- algebraic short-circuit, deterministic).
// ---------------------------------------------------------------------------
__global__ __launch_bounds__(256) void gram_kernel(
    const float* __restrict__ tmap, const float* __restrict__ rmap,
    const float* __restrict__ gamma, const float* __restrict__ omega,
    float* __restrict__ G)
{
    const int map = blockIdx.y;
    const float mult = (map == 0) ? omega[0] : gamma[0];
    if (mult == 0.f) return;

    __shared__ float tile[64][68];
    const int chunk = blockIdx.x;
    const int b     = blockIdx.z;
    const float* x = (map == 0 ? tmap : rmap) + (size_t)b * CH * NPIX + chunk * 512;
    const int t  = threadIdx.x;
    const int ti = t >> 4;
    const int tj = t & 15;

    float acc[4][4];
#pragma unroll
    for (int i = 0; i < 4; ++i)
#pragma unroll
        for (int j = 0; j < 4; ++j) acc[i][j] = 0.f;

    for (int tt = 0; tt < 8; ++tt) {
        const int col0 = tt * 64;
#pragma unroll
        for (int k = 0; k < 16; ++k) {
            int e = t + 256 * k;
            int c = e >> 6, col = e & 63;
            tile[c][col] = x[(size_t)c * NPIX + col0 + col];
        }
        __syncthreads();
#pragma unroll 8
        for (int n = 0; n < 64; n += 2) {
            float2 av[4], bv[4];
#pragma unroll
            for (int i = 0; i < 4; ++i) av[i] = *(const float2*)&tile[ti + 16 * i][n];
#pragma unroll
            for (int j = 0; j < 4; ++j) bv[j] = *(const float2*)&tile[tj + 16 * j][n];
#pragma unroll
            for (int i = 0; i < 4; ++i)
#pragma unroll
                for (int j = 0; j < 4; ++j) {
                    acc[i][j] += av[i].x * bv[j].x;
                    acc[i][j] += av[i].y * bv[j].y;
                }
        }
        __syncthreads();
    }
    float* Gp = G + ((size_t)(b * 2 + map) << 12);
#pragma unroll
    for (int i = 0; i < 4; ++i)
#pragma unroll
        for (int j = 0; j < 4; ++j)
            atomicAdd(&Gp[(ti + 16 * i) * 64 + (tj + 16 * j)], acc[i][j]);
}

// ---------------------------------------------------------------------------
// Kernel 2 (FUSED finalize + MFMA GEMM) -- the r12 optimum, reverted to
// exactly:
//   out[b](64 x 16384) = M[b](64x128) @ X(128x16384) + bias
//   M[o][k] = conv_w[o][k] + (k<64 ? gamma*(W1@r_attn)[o][k]
//                                  : omega*(W2@t_attn)[o][k-64])
// M built per block into LDS as bf16 A-fragments (zero path: repack conv_w).
// Pipeline: Xs[2][32][256] f32 ping-pong, DMA global_load_lds 1KB px-rows,
// counted s_waitcnt vmcnt(8), raw s_barrier, plain dword stores.
// LDS 80KB -> 2 blocks/CU; grid 64x16 = 1024 blocks; 256 thr = 4 waves.
// ---------------------------------------------------------------------------
__global__ __launch_bounds__(256, 2) void out_kernel(
    const float* __restrict__ tmap, const float* __restrict__ rmap,
    const float* __restrict__ G, const float* __restrict__ gamma,
    const float* __restrict__ omega, const float* __restrict__ conv_w,
    const float* __restrict__ conv_b, float* __restrict__ out)
{
    __shared__ __align__(16) uint   Xs[2][32][256];   // 64 KB ping-pong
    __shared__ __align__(16) ushort Ms[8192];         // 16 KB A-fragments

    const int b   = blockIdx.y;
    const int t   = threadIdx.x;
    const int w   = t >> 6;
    const int l   = t & 63;
    const int lg  = l >> 4;
    const int lj  = l & 15;
    const int px0 = blockIdx.x * 256;

    const float gam = gamma[0], om = omega[0];

    // ---- build M fragments in LDS ----
    if (gam != 0.f || om != 0.f) {
        float* attnf = (float*)&Xs[0][0][0];
        if (t < 128) {
            const int map = t >> 6, i = t & 63;
            const float need = (map == 0) ? om : gam;
            if (need != 0.f) {
                const float* Grow = G + ((size_t)(b * 2 + map) << 12) + i * 64;
                float mn = Grow[0];
                for (int j = 1; j < 64; ++j) mn = fminf(mn, Grow[j]);
                float s = 0.f;
                for (int j = 0; j < 64; ++j) s += expf(mn - Grow[j]);
                const float inv = 1.f / s;
                for (int j = 0; j < 64; ++j)
                    attnf[(map << 12) + i * 64 + j] = expf(mn - Grow[j]) * inv;
            }
        }
        __syncthreads();
#pragma unroll
        for (int j = 0; j < 32; ++j) {
            const int idx = t + 256 * j;
            const int e = idx & 7, ll = (idx >> 3) & 63;
            const int mi = (idx >> 9) & 3, kstep = idx >> 11;
            const int row = mi * 16 + (ll & 15);
            const int k   = kstep * 32 + (ll >> 4) * 8 + e;
            const float* wrow = conv_w + row * TWOC;
            float v = wrow[k];
            if (k < 64) {
                if (gam != 0.f) {
                    float dot = 0.f;
                    for (int c = 0; c < 64; ++c) dot += wrow[c] * attnf[(1 << 12) + c * 64 + k];
                    v += gam * dot;
                }
            } else {
                if (om != 0.f) {
                    float dot = 0.f;
                    for (int c = 0; c < 64; ++c) dot += wrow[64 + c] * attnf[c * 64 + (k - 64)];
                    v += om * dot;
                }
            }
            Ms[idx] = f2bf(v);
        }
        __syncthreads();   // attn reads done; Xs free for DMA; Ms visible
    } else {
        // zero path: M == conv_w, straight repack (no attn, no G)
#pragma unroll
        for (int j = 0; j < 32; ++j) {
            const int idx = t + 256 * j;
            const int e = idx & 7, ll = (idx >> 3) & 63;
            const int mi = (idx >> 9) & 3, kstep = idx >> 11;
            const int row = mi * 16 + (ll & 15);
            const int k   = kstep * 32 + (ll >> 4) * 8 + e;
            Ms[idx] = f2bf(conv_w[row * TWOC + k]);
        }
    }

    const float* tb = tmap + (size_t)b * CH * NPIX + px0;
    const float* rb = rmap + (size_t)b * CH * NPIX + px0;
#define SRC(c) (((c) < 2 ? tb : rb) + (size_t)(((c) & 1) * 32) * NPIX)

    // ---- prologue: queue chunks 0 and 1 (8 DMA ops each) ----
#pragma unroll
    for (int i = 0; i < 8; ++i) {
        const int row = i * 4 + w;
        gload16(SRC(0) + (size_t)row * NPIX + 4 * l, &Xs[0][row][0]);
    }
#pragma unroll
    for (int i = 0; i < 8; ++i) {
        const int row = i * 4 + w;
        gload16(SRC(1) + (size_t)row * NPIX + 4 * l, &Xs[1][row][0]);
    }

    // Ms visible to all waves
    asm volatile("s_waitcnt lgkmcnt(0)" ::: "memory");
    __builtin_amdgcn_s_barrier();
    __builtin_amdgcn_sched_barrier(0);

    // hoist all A-fragments to registers (16 x ds_read_b128)
    short8 a[4][4];
#pragma unroll
    for (int c = 0; c < 4; ++c)
#pragma unroll
        for (int mi = 0; mi < 4; ++mi)
            a[c][mi] = *(const short8*)&Ms[((c * 4 + mi) * 64 + l) * 8];

    floatx4 acc[4][4];
#pragma unroll
    for (int mi = 0; mi < 4; ++mi)
#pragma unroll
        for (int nj = 0; nj < 4; ++nj) acc[mi][nj] = (floatx4){0.f, 0.f, 0.f, 0.f};

#pragma unroll
    for (int c = 0; c < 4; ++c) {
        if (c < 3) { asm volatile("s_waitcnt vmcnt(8) lgkmcnt(0)" ::: "memory"); }
        else       { asm volatile("s_waitcnt vmcnt(0) lgkmcnt(0)" ::: "memory"); }
        __builtin_amdgcn_sched_barrier(0);
        __builtin_amdgcn_s_barrier();
        __builtin_amdgcn_sched_barrier(0);

        // compute chunk c from Xs[c&1]
#pragma unroll
        for (int nj = 0; nj < 4; ++nj) {
            const int pxl = w * 64 + nj * 16 + lj;
            float v[8];
#pragma unroll
            for (int e = 0; e < 8; ++e)
                v[e] = __uint_as_float(Xs[c & 1][8 * lg + e][pxl]);
            uint4 bu;
            bu.x = pk2(v[0], v[1]);
            bu.y = pk2(v[2], v[3]);
            bu.z = pk2(v[4], v[5]);
            bu.w = pk2(v[6], v[7]);
            const short8 bb = *(const short8*)&bu;
#pragma unroll
            for (int mi = 0; mi < 4; ++mi)
                acc[mi][nj] = __builtin_amdgcn_mfma_f32_16x16x32_bf16(
                    a[c][mi], bb, acc[mi][nj], 0, 0, 0);
        }

        // release buffer
        asm volatile("s_waitcnt lgkmcnt(0)" ::: "memory");
        __builtin_amdgcn_sched_barrier(0);
        __builtin_amdgcn_s_barrier();
        __builtin_amdgcn_sched_barrier(0);

        // refill with chunk c+2
        if (c < 2) {
            const int cn = c + 2;
#pragma unroll
            for (int i = 0; i < 8; ++i) {
                const int row = i * 4 + w;
                gload16(SRC(cn) + (size_t)row * NPIX + 4 * l, &Xs[c & 1][row][0]);
            }
        }
    }
#undef SRC

    // epilogue: C/D layout col=lane&15, row=(lane>>4)*4+reg (guide m89/m91)
    const int pxw = px0 + w * 64;
#pragma unroll
    for (int mi = 0; mi < 4; ++mi) {
#pragma unroll
        for (int r = 0; r < 4; ++r) {
            const int och = mi * 16 + lg * 4 + r;
            const float bv = conv_b[och];
            float* orow = out + ((size_t)b * CH + och) * NPIX;
#pragma unroll
            for (int nj = 0; nj < 4; ++nj)
                orow[pxw + nj * 16 + lj] = acc[mi][nj][r] + bv;
        }
    }
}

// ---------------------------------------------------------------------------
extern "C" void kernel_launch(void* const* d_in, const int* in_sizes, int n_in,
                              void* d_out, int out_size, void* d_ws, size_t ws_size,
                              hipStream_t stream) {
    const float* tmap   = (const float*)d_in[0];
    const float* rmap   = (const float*)d_in[1];
    const float* gamma  = (const float*)d_in[2];
    const float* omega  = (const float*)d_in[3];
    const float* conv_w = (const float*)d_in[4];
    const float* conv_b = (const float*)d_in[5];
    float* out = (float*)d_out;

    // ws layout: G [16][2][4096] fp32 (512 KiB)
    float* G = (float*)d_ws;

    hipMemsetAsync(d_ws, 0, (size_t)BATCH * 2 * 4096 * sizeof(float), stream);

    gram_kernel<<<dim3(32, 2, BATCH), 256, 0, stream>>>(tmap, rmap, gamma, omega, G);
    out_kernel<<<dim3(64, BATCH), 256, 0, stream>>>(tmap, rmap, G, gamma, omega,
                                                    conv_w, conv_b, out);
}